// Round 2
// baseline (81.738 us; speedup 1.0000x reference)
//
#include <hip/hip_runtime.h>

// Problem constants: B=16, C=5, H=512, W=512
constexpr int Bn      = 16;
constexpr int Cn      = 5;
constexpr int HW      = 512 * 512;        // 262144
constexpr int HW4     = HW / 4;           // 65536 float4 groups per (b,c) plane
constexpr int NVEC    = Bn * HW / 4;      // 1,048,576 4-pixel groups
constexpr int NBLK    = 2048;
constexpr int THREADS = 256;
constexpr int STRIDE  = NBLK * THREADS;   // 524288 == NVEC/2; v1 = v0+STRIDE => b+8, same hw
constexpr float SCALE = 1.0f / (float)(Bn * HW);

__device__ __forceinline__ float block_reduce_256(float v) {
    #pragma unroll
    for (int off = 32; off > 0; off >>= 1)
        v += __shfl_down(v, off, 64);
    __shared__ float s[4];
    const int lane = threadIdx.x & 63;
    const int wid  = threadIdx.x >> 6;
    if (lane == 0) s[wid] = v;
    __syncthreads();
    if (threadIdx.x == 0) v = (s[0] + s[1]) + (s[2] + s[3]);
    return v;
}

__device__ __forceinline__ float pixel_pen(float l0, float l1, float l2, float l3,
                                           float l4, int t) {
    // relu terms on unnormalized exps; single divide by partition sum (S>0).
    float m  = fmaxf(fmaxf(fmaxf(l0, l1), fmaxf(l2, l3)), l4);
    float e0 = __expf(l0 - m);
    float e1 = __expf(l1 - m);
    float e2 = __expf(l2 - m);
    float e3 = __expf(l3 - m);
    float e4 = __expf(l4 - m);
    float S  = ((e0 + e1) + (e2 + e3)) + e4;
    float d1 = e1 - e0;
    float d2 = e2 - e1;
    float d3 = e3 - e2;
    float d4 = e4 - e3;
    float pen = 0.0f;
    pen += (t >= 1) ? fmaxf(-d1, 0.0f) : fmaxf(d1, 0.0f);
    pen += (t >= 2) ? fmaxf(-d2, 0.0f) : fmaxf(d2, 0.0f);
    pen += (t >= 3) ? fmaxf(-d3, 0.0f) : fmaxf(d3, 0.0f);
    pen += (t >= 4) ? fmaxf(-d4, 0.0f) : fmaxf(d4, 0.0f);
    return pen / S;
}

__device__ __forceinline__ float group_pen(float4 x0, float4 x1, float4 x2,
                                           float4 x3, float4 x4, int4 t) {
    float a = 0.0f;
    a += pixel_pen(x0.x, x1.x, x2.x, x3.x, x4.x, t.x);
    a += pixel_pen(x0.y, x1.y, x2.y, x3.y, x4.y, t.y);
    a += pixel_pen(x0.z, x1.z, x2.z, x3.z, x4.z, t.z);
    a += pixel_pen(x0.w, x1.w, x2.w, x3.w, x4.w, t.w);
    return a;
}

__global__ void __launch_bounds__(256)
o2_loss_fused(const float4* __restrict__ pred,   // (B, 5, H, W) as float4
              const int4*  __restrict__ lab,     // (B, H, W) as int4
              float* __restrict__ partial,       // d_ws: 2048 floats
              unsigned* __restrict__ cnt,        // d_ws + 8192 bytes
              float* __restrict__ out) {
    const int tid = threadIdx.x;
    const int v0  = blockIdx.x * THREADS + tid;   // in [0, STRIDE)
    // v1 = v0 + STRIDE: same hw4 offset, batch index + 8
    const int b0  = v0 >> 16;
    const int h0  = v0 & (HW4 - 1);
    const float4* p0 = pred + (size_t)b0 * (Cn * HW4) + h0;
    const float4* p1 = p0 + 8 * (Cn * HW4);

    // Issue all 12 pred loads + 2 label loads up front for MLP.
    float4 a0 = p0[0 * HW4], a1 = p0[1 * HW4], a2 = p0[2 * HW4],
           a3 = p0[3 * HW4], a4 = p0[4 * HW4];
    float4 b0v = p1[0 * HW4], b1v = p1[1 * HW4], b2v = p1[2 * HW4],
           b3v = p1[3 * HW4], b4v = p1[4 * HW4];
    int4 t0 = lab[v0];
    int4 t1 = lab[v0 + STRIDE];

    float acc = group_pen(a0, a1, a2, a3, a4, t0)
              + group_pen(b0v, b1v, b2v, b3v, b4v, t1);

    float bsum = block_reduce_256(acc);   // valid in thread 0

    __shared__ int is_last;
    if (tid == 0) {
        __hip_atomic_store(&partial[blockIdx.x], bsum,
                           __ATOMIC_RELAXED, __HIP_MEMORY_SCOPE_AGENT);
        unsigned old = __hip_atomic_fetch_add(cnt, 1u,
                           __ATOMIC_ACQ_REL, __HIP_MEMORY_SCOPE_AGENT);
        // Exactly 2048 increments per call -> fires exactly once per call,
        // for ANY initial counter value (poison-safe, replay-safe).
        is_last = ((old & (NBLK - 1)) == (NBLK - 1)) ? 1 : 0;
    }
    __syncthreads();

    if (is_last) {
        float v = 0.0f;
        for (int i = tid; i < NBLK; i += THREADS)   // fixed order -> deterministic
            v += __hip_atomic_load(&partial[i],
                                   __ATOMIC_RELAXED, __HIP_MEMORY_SCOPE_AGENT);
        v = block_reduce_256(v);
        if (tid == 0) out[0] = v * SCALE;
    }
}

extern "C" void kernel_launch(void* const* d_in, const int* in_sizes, int n_in,
                              void* d_out, int out_size, void* d_ws, size_t ws_size,
                              hipStream_t stream) {
    const float4* pred = (const float4*)d_in[0];
    const int4*   lab  = (const int4*)d_in[1];
    float*    partial  = (float*)d_ws;
    unsigned* cnt      = (unsigned*)((char*)d_ws + NBLK * sizeof(float));
    float*    out      = (float*)d_out;

    o2_loss_fused<<<NBLK, THREADS, 0, stream>>>(pred, lab, partial, cnt, out);
}

// Round 3
// 37.432 us; speedup vs baseline: 2.1836x; 2.1836x over previous
//
#include <hip/hip_runtime.h>

// Problem constants: B=16, C=5, H=512, W=512
constexpr int Bn      = 16;
constexpr int Cn      = 5;
constexpr int HW      = 512 * 512;        // 262144
constexpr int HW4     = HW / 4;           // 65536 float4 groups per (b,c) plane
constexpr int NVEC    = Bn * HW / 4;      // 1,048,576 4-pixel groups
constexpr int NBLK    = 2048;
constexpr int THREADS = 256;
constexpr int STRIDE  = NBLK * THREADS;   // 524288 == NVEC/2; v1 = v0+STRIDE => b+8, same hw
constexpr float SCALE = 1.0f / (float)(Bn * HW);

__device__ __forceinline__ float block_reduce_256(float v) {
    #pragma unroll
    for (int off = 32; off > 0; off >>= 1)
        v += __shfl_down(v, off, 64);
    __shared__ float s[4];
    const int lane = threadIdx.x & 63;
    const int wid  = threadIdx.x >> 6;
    if (lane == 0) s[wid] = v;
    __syncthreads();
    if (threadIdx.x == 0) v = (s[0] + s[1]) + (s[2] + s[3]);
    return v;
}

__device__ __forceinline__ float pixel_pen(float l0, float l1, float l2, float l3,
                                           float l4, int t) {
    // relu terms on unnormalized exps; single divide by partition sum (S>0).
    float m  = fmaxf(fmaxf(fmaxf(l0, l1), fmaxf(l2, l3)), l4);
    float e0 = __expf(l0 - m);
    float e1 = __expf(l1 - m);
    float e2 = __expf(l2 - m);
    float e3 = __expf(l3 - m);
    float e4 = __expf(l4 - m);
    float S  = ((e0 + e1) + (e2 + e3)) + e4;
    float d1 = e1 - e0;
    float d2 = e2 - e1;
    float d3 = e3 - e2;
    float d4 = e4 - e3;
    float pen = 0.0f;
    pen += (t >= 1) ? fmaxf(-d1, 0.0f) : fmaxf(d1, 0.0f);
    pen += (t >= 2) ? fmaxf(-d2, 0.0f) : fmaxf(d2, 0.0f);
    pen += (t >= 3) ? fmaxf(-d3, 0.0f) : fmaxf(d3, 0.0f);
    pen += (t >= 4) ? fmaxf(-d4, 0.0f) : fmaxf(d4, 0.0f);
    return pen / S;
}

__device__ __forceinline__ float group_pen(float4 x0, float4 x1, float4 x2,
                                           float4 x3, float4 x4, int4 t) {
    float a = 0.0f;
    a += pixel_pen(x0.x, x1.x, x2.x, x3.x, x4.x, t.x);
    a += pixel_pen(x0.y, x1.y, x2.y, x3.y, x4.y, t.y);
    a += pixel_pen(x0.z, x1.z, x2.z, x3.z, x4.z, t.z);
    a += pixel_pen(x0.w, x1.w, x2.w, x3.w, x4.w, t.w);
    return a;
}

__global__ void __launch_bounds__(256)
o2_loss_fused(const float4* __restrict__ pred,   // (B, 5, H, W) as float4
              const int4*  __restrict__ lab,     // (B, H, W) as int4
              float* __restrict__ partial,       // d_ws: 2048 floats
              unsigned* __restrict__ cnt,        // d_ws + 8192 bytes
              float* __restrict__ out) {
    const int tid = threadIdx.x;
    const int v0  = blockIdx.x * THREADS + tid;   // in [0, STRIDE)
    // v1 = v0 + STRIDE: same hw4 offset, batch index + 8
    const int b0  = v0 >> 16;
    const int h0  = v0 & (HW4 - 1);
    const float4* p0 = pred + (size_t)b0 * (Cn * HW4) + h0;
    const float4* p1 = p0 + 8 * (Cn * HW4);

    // Issue all 10 pred loads + 2 label loads up front for MLP.
    float4 a0 = p0[0 * HW4], a1 = p0[1 * HW4], a2 = p0[2 * HW4],
           a3 = p0[3 * HW4], a4 = p0[4 * HW4];
    float4 c0 = p1[0 * HW4], c1 = p1[1 * HW4], c2 = p1[2 * HW4],
           c3 = p1[3 * HW4], c4 = p1[4 * HW4];
    int4 t0 = lab[v0];
    int4 t1 = lab[v0 + STRIDE];

    float acc = group_pen(a0, a1, a2, a3, a4, t0)
              + group_pen(c0, c1, c2, c3, c4, t1);

    float bsum = block_reduce_256(acc);   // valid in thread 0

    __shared__ int is_last;
    if (tid == 0) {
        // Relaxed agent-scope ops only: sc1 (coherence-point) accesses,
        // NO buffer_wbl2 / buffer_inv L2 flushes (the round-2 regression).
        __hip_atomic_store(&partial[blockIdx.x], bsum,
                           __ATOMIC_RELAXED, __HIP_MEMORY_SCOPE_AGENT);
        // Per-wave ordering: my store is ack'd at the coherence point
        // before my counter increment can be observed. No cache flush.
        asm volatile("s_waitcnt vmcnt(0)" ::: "memory");
        unsigned old = __hip_atomic_fetch_add(cnt, 1u,
                           __ATOMIC_RELAXED, __HIP_MEMORY_SCOPE_AGENT);
        // Exactly 2048 increments per call -> fires exactly once per call,
        // for ANY initial counter value (poison-safe, replay-safe).
        is_last = ((old & (NBLK - 1)) == (NBLK - 1)) ? 1 : 0;
    }
    __syncthreads();

    if (is_last) {
        float v = 0.0f;
        for (int i = tid; i < NBLK; i += THREADS)   // fixed order -> deterministic
            v += __hip_atomic_load(&partial[i],
                                   __ATOMIC_RELAXED, __HIP_MEMORY_SCOPE_AGENT);
        v = block_reduce_256(v);
        if (tid == 0) out[0] = v * SCALE;
    }
}

extern "C" void kernel_launch(void* const* d_in, const int* in_sizes, int n_in,
                              void* d_out, int out_size, void* d_ws, size_t ws_size,
                              hipStream_t stream) {
    const float4* pred = (const float4*)d_in[0];
    const int4*   lab  = (const int4*)d_in[1];
    float*    partial  = (float*)d_ws;
    unsigned* cnt      = (unsigned*)((char*)d_ws + NBLK * sizeof(float));
    float*    out      = (float*)d_out;

    o2_loss_fused<<<NBLK, THREADS, 0, stream>>>(pred, lab, partial, cnt, out);
}

// Round 4
// 23.504 us; speedup vs baseline: 3.4776x; 1.5926x over previous
//
#include <hip/hip_runtime.h>

// Problem constants: B=16, C=5, H=512, W=512
constexpr int Bn      = 16;
constexpr int Cn      = 5;
constexpr int HW      = 512 * 512;        // 262144
constexpr int HW4     = HW / 4;           // 65536 float4 groups per (b,c) plane
constexpr int NVEC    = Bn * HW / 4;      // 1,048,576 4-pixel groups
constexpr int NBLK    = 2048;
constexpr int THREADS = 256;
constexpr int STRIDE  = NBLK * THREADS;   // 524288 == NVEC/2; +STRIDE => batch+8, same hw4
constexpr float SCALE = 1.0f / (float)(Bn * HW);

__device__ __forceinline__ float block_reduce_256(float v) {
    #pragma unroll
    for (int off = 32; off > 0; off >>= 1)
        v += __shfl_down(v, off, 64);
    __shared__ float s[4];
    const int lane = threadIdx.x & 63;
    const int wid  = threadIdx.x >> 6;
    if (lane == 0) s[wid] = v;
    __syncthreads();
    if (threadIdx.x == 0) v = (s[0] + s[1]) + (s[2] + s[3]);
    return v;
}

__device__ __forceinline__ float pixel_pen(float l0, float l1, float l2, float l3,
                                           float l4, int t) {
    // relu terms on unnormalized exps; single divide by partition sum (S>0).
    float m  = fmaxf(fmaxf(fmaxf(l0, l1), fmaxf(l2, l3)), l4);
    float e0 = __expf(l0 - m);
    float e1 = __expf(l1 - m);
    float e2 = __expf(l2 - m);
    float e3 = __expf(l3 - m);
    float e4 = __expf(l4 - m);
    float S  = ((e0 + e1) + (e2 + e3)) + e4;
    float d1 = e1 - e0;
    float d2 = e2 - e1;
    float d3 = e3 - e2;
    float d4 = e4 - e3;
    float pen = 0.0f;
    pen += (t >= 1) ? fmaxf(-d1, 0.0f) : fmaxf(d1, 0.0f);
    pen += (t >= 2) ? fmaxf(-d2, 0.0f) : fmaxf(d2, 0.0f);
    pen += (t >= 3) ? fmaxf(-d3, 0.0f) : fmaxf(d3, 0.0f);
    pen += (t >= 4) ? fmaxf(-d4, 0.0f) : fmaxf(d4, 0.0f);
    return pen / S;
}

__device__ __forceinline__ float group_pen(float4 x0, float4 x1, float4 x2,
                                           float4 x3, float4 x4, int4 t) {
    float a = 0.0f;
    a += pixel_pen(x0.x, x1.x, x2.x, x3.x, x4.x, t.x);
    a += pixel_pen(x0.y, x1.y, x2.y, x3.y, x4.y, t.y);
    a += pixel_pen(x0.z, x1.z, x2.z, x3.z, x4.z, t.z);
    a += pixel_pen(x0.w, x1.w, x2.w, x3.w, x4.w, t.w);
    return a;
}

// min 4 waves/SIMD -> up to ~128 VGPRs: room to keep all 14 loads in flight.
__global__ void __launch_bounds__(256, 4)
o2_loss_partial(const float4* __restrict__ pred,   // (B, 5, H, W) as float4
                const int4*  __restrict__ lab,     // (B, H, W) as int4
                float* __restrict__ partial) {
    const int tid = threadIdx.x;
    const int v0  = blockIdx.x * THREADS + tid;   // in [0, STRIDE)
    const int b0  = v0 >> 16;
    const int h0  = v0 & (HW4 - 1);
    const float4* p0 = pred + (size_t)b0 * (Cn * HW4) + h0;
    const float4* p1 = p0 + 8 * (Cn * HW4);       // batch+8, same hw4

    // Issue ALL loads up front; with 128-VGPR budget they stay in flight.
    float4 a0 = p0[0 * HW4], a1 = p0[1 * HW4], a2 = p0[2 * HW4],
           a3 = p0[3 * HW4], a4 = p0[4 * HW4];
    float4 c0 = p1[0 * HW4], c1 = p1[1 * HW4], c2 = p1[2 * HW4],
           c3 = p1[3 * HW4], c4 = p1[4 * HW4];
    int4 t0 = lab[v0];
    int4 t1 = lab[v0 + STRIDE];

    float acc = group_pen(a0, a1, a2, a3, a4, t0)
              + group_pen(c0, c1, c2, c3, c4, t1);

    float bsum = block_reduce_256(acc);
    if (tid == 0) partial[blockIdx.x] = bsum;     // plain store, no atomics
}

__global__ void __launch_bounds__(256)
o2_loss_finalize(const float4* __restrict__ partial4, float* __restrict__ out) {
    // 2048 floats = 512 float4; each thread sums 2 in fixed order.
    float4 x = partial4[threadIdx.x];
    float4 y = partial4[threadIdx.x + 256];
    float v = ((x.x + x.y) + (x.z + x.w)) + ((y.x + y.y) + (y.z + y.w));
    v = block_reduce_256(v);
    if (threadIdx.x == 0) out[0] = v * SCALE;
}

extern "C" void kernel_launch(void* const* d_in, const int* in_sizes, int n_in,
                              void* d_out, int out_size, void* d_ws, size_t ws_size,
                              hipStream_t stream) {
    const float4* pred = (const float4*)d_in[0];
    const int4*   lab  = (const int4*)d_in[1];
    float* partial = (float*)d_ws;          // 2048 floats = 8 KB scratch
    float* out     = (float*)d_out;

    o2_loss_partial<<<NBLK, THREADS, 0, stream>>>(pred, lab, partial);
    o2_loss_finalize<<<1, THREADS, 0, stream>>>((const float4*)partial, out);
}